// Round 1
// 1511.006 us; speedup vs baseline: 1.0397x; 1.0397x over previous
//
#include <hip/hip_runtime.h>
#include <math.h>

namespace {
constexpr int N_ = 8;
constexpr int C_ = 256;
constexpr int H_ = 192;   // feature H
constexpr int W_ = 320;   // feature W
constexpr int SH = 768;   // full-res H
constexpr int SW = 1280;  // full-res W
constexpr int HW = H_ * W_;
constexpr long long FUSED_SIZE = (long long)N_ * C_ * HW;  // 125,829,120

constexpr int CCHUNK = 64;                       // channels per block
constexpr int NCC = C_ / CCHUNK;                 // 4 channel chunks
constexpr int XBLK = W_ / 64;                    // 5 wave-sized x segments
constexpr int FUSE_NWG = NCC * N_ * H_ * XBLK;   // 30720 blocks (one wave each)
}  // namespace

// ---------------------------------------------------------------------------
// Kernel 1: fused = (rm1*fmap1 + rm1n*warped(fmap1_next)) / (rm1 + rm1n)
// One block = ONE WAVE (64 threads) covering a 64-px x-segment of one feature
// row, for a 64-channel chunk. 30720 blocks total (wave-granular occupancy).
// Bijective chunked XCD swizzle keeps contiguous y (which gather from
// overlapping fmap1_next rows) on the same XCD's L2. fmap1 read and fused
// write are non-temporal (single-touch) to preserve L2/L3 for the gathers.
// ---------------------------------------------------------------------------
__global__ __launch_bounds__(64) void fuse_kernel(
    const float* __restrict__ fmap1, const float* __restrict__ fmap1_next,
    const float* __restrict__ flow_left, const float* __restrict__ mask1,
    const float* __restrict__ mask1_next, float* __restrict__ out) {
  // chunked XCD swizzle: FUSE_NWG % 8 == 0, bijective
  int bid = blockIdx.x;
  int lid = (bid & 7) * (FUSE_NWG / 8) + (bid >> 3);
  // layout: lid = ((cc*N + n)*H + y)*XBLK + xb   (y contiguous within chunk)
  int xb = lid % XBLK;
  int r = lid / XBLK;
  int y = r % H_;
  int t = r / H_;
  int n = t & 7;    // N_ == 8
  int cc = t >> 3;  // 0..NCC-1
  int x = xb * 64 + threadIdx.x;  // 0..319

  // Bilinear 4x-downsample: src coords ys = 4y+1.5 -> taps (4y+1, 4y+2), w=0.5
  const int sy = 4 * y + 1;
  const int sx = 4 * x + 1;
  const size_t sbase = (size_t)sy * SW + sx;

  // resized flow (with 0.25 component scale)
  const float* fl = flow_left + (size_t)n * 2 * SH * SW;
  const float* flx = fl;
  const float* fly = fl + (size_t)SH * SW;
  float rfx = 0.25f * (0.5f * (0.5f * flx[sbase] + 0.5f * flx[sbase + 1]) +
                       0.5f * (0.5f * flx[sbase + SW] + 0.5f * flx[sbase + SW + 1]));
  float rfy = 0.25f * (0.5f * (0.5f * fly[sbase] + 0.5f * fly[sbase + 1]) +
                       0.5f * (0.5f * fly[sbase + SW] + 0.5f * fly[sbase + SW + 1]));

  // grid_sample source coords (align_corners=False round-trip)
  float px = (x + rfx) * (320.0f / 319.0f) - 0.5f;
  float py = (y + rfy) * (192.0f / 191.0f) - 0.5f;
  float x0f = floorf(px), y0f = floorf(py);
  int x0 = (int)x0f, y0 = (int)y0f;
  float wx = px - x0f, wy = py - y0f;
  int x1 = x0 + 1, y1 = y0 + 1;
  bool vx0 = (x0 >= 0) & (x0 < W_), vx1 = (x1 >= 0) & (x1 < W_);
  bool vy0 = (y0 >= 0) & (y0 < H_), vy1 = (y1 >= 0) & (y1 < H_);
  int cx0 = min(max(x0, 0), W_ - 1), cx1 = min(max(x1, 0), W_ - 1);
  int cy0 = min(max(y0, 0), H_ - 1), cy1 = min(max(y1, 0), H_ - 1);
  int o00 = cy0 * W_ + cx0, o01 = cy0 * W_ + cx1;
  int o10 = cy1 * W_ + cx0, o11 = cy1 * W_ + cx1;
  float w00 = (vy0 && vx0) ? (1.0f - wx) * (1.0f - wy) : 0.0f;
  float w01 = (vy0 && vx1) ? wx * (1.0f - wy) : 0.0f;
  float w10 = (vy1 && vx0) ? (1.0f - wx) * wy : 0.0f;
  float w11 = (vy1 && vx1) ? wx * wy : 0.0f;

  // rm1 = resize(mask1) at (y,x)
  const float* m1 = mask1 + (size_t)n * SH * SW;
  float rm1 = 0.5f * (0.5f * m1[sbase] + 0.5f * m1[sbase + 1]) +
              0.5f * (0.5f * m1[sbase + SW] + 0.5f * m1[sbase + SW + 1]);

  // rm1n = grid_sample(resize(mask1_next)) at (px,py): 4 taps, each tap is a
  // 2x2 bilinear average of mask1_next at the resized-grid integer location.
  const float* m1n = mask1_next + (size_t)n * SH * SW;
  auto rmn_at = [&](int yy, int xx) -> float {
    size_t b = (size_t)(4 * yy + 1) * SW + (4 * xx + 1);
    return 0.5f * (0.5f * m1n[b] + 0.5f * m1n[b + 1]) +
           0.5f * (0.5f * m1n[b + SW] + 0.5f * m1n[b + SW + 1]);
  };
  float rm1n = w00 * rmn_at(cy0, cx0) + w01 * rmn_at(cy0, cx1) +
               w10 * rmn_at(cy1, cx0) + w11 * rmn_at(cy1, cx1);

  float s = rm1 + rm1n;
  if (s == 0.0f) s = 1e-6f;
  float a = rm1 / s;
  float b = rm1n / s;
  float bw00 = b * w00, bw01 = b * w01, bw10 = b * w10, bw11 = b * w11;

  const int c0 = cc * CCHUNK;
  const float* f1 = fmap1 + ((size_t)n * C_ + c0) * HW + y * W_ + x;
  const float* f2 = fmap1_next + ((size_t)n * C_ + c0) * HW;
  float* o = out + ((size_t)n * C_ + c0) * HW + y * W_ + x;

#pragma unroll 8
  for (int c = 0; c < CCHUNK; ++c) {
    const float* p = f2 + (size_t)c * HW;
    float v1 = __builtin_nontemporal_load(&f1[(size_t)c * HW]);
    float wv = bw00 * p[o00] + bw01 * p[o01] + bw10 * p[o10] + bw11 * p[o11];
    __builtin_nontemporal_store(a * v1 + wv, &o[(size_t)c * HW]);
  }
}

// ---------------------------------------------------------------------------
// Kernel 2: convex upsample of coarse_flow channel 0 with up_mask, factor 4.
// (unchanged from previous round — isolates the fuse_kernel delta)
// ---------------------------------------------------------------------------
__global__ __launch_bounds__(W_) void upsample_kernel(
    const float* __restrict__ coarse_flow, const float* __restrict__ up_mask,
    float* __restrict__ out) {
  int b = blockIdx.x;
  int h = b % H_;
  b /= H_;
  int fy = b & 3;
  int n = b >> 2;
  int w = threadIdx.x;

  // 3x3 neighborhood of 4*flow[:,0], zero-padded
  const float* f = coarse_flow + (size_t)n * 2 * HW;
  float nb[9];
#pragma unroll
  for (int dy = 0; dy < 3; ++dy) {
#pragma unroll
    for (int dx = 0; dx < 3; ++dx) {
      int yy = h + dy - 1, xx = w + dx - 1;
      nb[dy * 3 + dx] = (yy >= 0 && yy < H_ && xx >= 0 && xx < W_)
                            ? 4.0f * f[yy * W_ + xx]
                            : 0.0f;
    }
  }

  const float* mb = up_mask + ((size_t)n * 144 * H_ + (size_t)h) * W_ + w;
  float4 res;
  float* resp = &res.x;
#pragma unroll
  for (int fx = 0; fx < 4; ++fx) {
    int cbase = fy * 4 + fx;
    float mv[9];
#pragma unroll
    for (int k = 0; k < 9; ++k)
      mv[k] = mb[(size_t)(k * 16 + cbase) * HW];
    float mx = mv[0];
#pragma unroll
    for (int k = 1; k < 9; ++k) mx = fmaxf(mx, mv[k]);
    float sum = 0.0f, acc = 0.0f;
#pragma unroll
    for (int k = 0; k < 9; ++k) {
      float e = __expf(mv[k] - mx);
      sum += e;
      acc += e * nb[k];
    }
    resp[fx] = acc / sum;
  }
  float* orow = out + (size_t)(n * SH + 4 * h + fy) * SW;
  *(float4*)(orow + 4 * w) = res;
}

extern "C" void kernel_launch(void* const* d_in, const int* in_sizes, int n_in,
                              void* d_out, int out_size, void* d_ws,
                              size_t ws_size, hipStream_t stream) {
  const float* fmap1 = (const float*)d_in[0];
  const float* fmap1_next = (const float*)d_in[1];
  const float* flow_left = (const float*)d_in[2];
  const float* mask1 = (const float*)d_in[3];
  const float* mask1_next = (const float*)d_in[4];
  const float* coarse_flow = (const float*)d_in[5];
  const float* up_mask = (const float*)d_in[6];
  float* out = (float*)d_out;

  fuse_kernel<<<FUSE_NWG, 64, 0, stream>>>(fmap1, fmap1_next, flow_left, mask1,
                                           mask1_next, out);
  upsample_kernel<<<N_ * 4 * H_, W_, 0, stream>>>(coarse_flow, up_mask,
                                                  out + FUSED_SIZE);
}

// Round 2
// 1425.345 us; speedup vs baseline: 1.1021x; 1.0601x over previous
//
#include <hip/hip_runtime.h>
#include <math.h>

namespace {
constexpr int N_ = 8;
constexpr int C_ = 256;
constexpr int H_ = 192;   // feature H
constexpr int W_ = 320;   // feature W
constexpr int SH = 768;   // full-res H
constexpr int SW = 1280;  // full-res W
constexpr int HW = H_ * W_;
constexpr long long FUSED_SIZE = (long long)N_ * C_ * HW;  // 125,829,120

constexpr int CCHUNK = 64;                      // channels per block
constexpr int NCC = C_ / CCHUNK;                // 4 channel chunks
constexpr int TPB = 256;                        // 4 waves per block
constexpr int PXB = TPB;                        // 256 pixels per block (1 px/lane)
constexpr int PB = HW / PXB;                    // 240 pixel-blocks per (cc,n)
constexpr int FUSE_NWG = NCC * N_ * PB;         // 7680 blocks, %8==0
}  // namespace

// 8B gather load; memcpy keeps it correct even if the backend splits it.
// With unaligned-access-mode (default on gfx950/HSA) this emits
// global_load_dwordx2 at the 4B-aligned address.
__device__ __forceinline__ float2 ld2(const float* p) {
  float2 v;
  __builtin_memcpy(&v, p, sizeof(float2));
  return v;
}

// ---------------------------------------------------------------------------
// Kernel 1: fused = (rm1*fmap1 + rm1n*warped(fmap1_next)) / (rm1 + rm1n)
// 256-thread blocks (4 waves) over flattened feature pixels, 64-channel
// chunks. Inner loop per channel: 2 x-pair float2 gathers (taps folded into
// per-pixel wA/wB weights in the preamble) + 1 NT fmap1 load + 1 NT store
// = 4 VMEM ops/channel (was 6). Bijective chunked XCD swizzle keeps the
// rolling gather window of fmap1_next resident in each XCD's L2.
// ---------------------------------------------------------------------------
__global__ __launch_bounds__(TPB, 8) void fuse_kernel(
    const float* __restrict__ fmap1, const float* __restrict__ fmap1_next,
    const float* __restrict__ flow_left, const float* __restrict__ mask1,
    const float* __restrict__ mask1_next, float* __restrict__ out) {
  // chunked XCD swizzle: FUSE_NWG % 8 == 0, bijective
  int bid = blockIdx.x;
  int lid = (bid & 7) * (FUSE_NWG / 8) + (bid >> 3);
  // layout: lid = ((cc*N + n)*PB + pb)   (pixel-blocks contiguous per chunk)
  int pb = lid % PB;
  int g = lid / PB;
  int n = g & 7;    // N_ == 8
  int cc = g >> 3;  // 0..NCC-1
  int p = pb * PXB + (int)threadIdx.x;  // flattened pixel 0..61439
  int y = p / W_;
  int x = p % W_;

  // Bilinear 4x-downsample: src coords ys = 4y+1.5 -> taps (4y+1, 4y+2), w=0.5
  const int sy = 4 * y + 1;
  const int sx = 4 * x + 1;
  const size_t sbase = (size_t)sy * SW + sx;

  // resized flow (with 0.25 component scale)
  const float* fl = flow_left + (size_t)n * 2 * SH * SW;
  const float* flx = fl;
  const float* fly = fl + (size_t)SH * SW;
  float rfx = 0.25f * (0.5f * (0.5f * flx[sbase] + 0.5f * flx[sbase + 1]) +
                       0.5f * (0.5f * flx[sbase + SW] + 0.5f * flx[sbase + SW + 1]));
  float rfy = 0.25f * (0.5f * (0.5f * fly[sbase] + 0.5f * fly[sbase + 1]) +
                       0.5f * (0.5f * fly[sbase + SW] + 0.5f * fly[sbase + SW + 1]));

  // grid_sample source coords (align_corners=False round-trip)
  float px = (x + rfx) * (320.0f / 319.0f) - 0.5f;
  float py = (y + rfy) * (192.0f / 191.0f) - 0.5f;
  float x0f = floorf(px), y0f = floorf(py);
  int x0 = (int)x0f, y0 = (int)y0f;
  float wx = px - x0f, wy = py - y0f;
  int x1 = x0 + 1, y1 = y0 + 1;
  bool vx0 = (x0 >= 0) & (x0 < W_), vx1 = (x1 >= 0) & (x1 < W_);
  bool vy0 = (y0 >= 0) & (y0 < H_), vy1 = (y1 >= 0) & (y1 < H_);
  int cx0 = min(max(x0, 0), W_ - 1), cx1 = min(max(x1, 0), W_ - 1);
  int cy0 = min(max(y0, 0), H_ - 1), cy1 = min(max(y1, 0), H_ - 1);
  float w00 = (vy0 && vx0) ? (1.0f - wx) * (1.0f - wy) : 0.0f;
  float w01 = (vy0 && vx1) ? wx * (1.0f - wy) : 0.0f;
  float w10 = (vy1 && vx0) ? (1.0f - wx) * wy : 0.0f;
  float w11 = (vy1 && vx1) ? wx * wy : 0.0f;

  // rm1 = resize(mask1) at (y,x)
  const float* m1 = mask1 + (size_t)n * SH * SW;
  float rm1 = 0.5f * (0.5f * m1[sbase] + 0.5f * m1[sbase + 1]) +
              0.5f * (0.5f * m1[sbase + SW] + 0.5f * m1[sbase + SW + 1]);

  // rm1n = grid_sample(resize(mask1_next)) at (px,py): 4 taps, each tap is a
  // 2x2 bilinear average of mask1_next at the resized-grid integer location.
  const float* m1n = mask1_next + (size_t)n * SH * SW;
  auto rmn_at = [&](int yy, int xx) -> float {
    size_t b = (size_t)(4 * yy + 1) * SW + (4 * xx + 1);
    return 0.5f * (0.5f * m1n[b] + 0.5f * m1n[b + 1]) +
           0.5f * (0.5f * m1n[b + SW] + 0.5f * m1n[b + SW + 1]);
  };
  float rm1n = w00 * rmn_at(cy0, cx0) + w01 * rmn_at(cy0, cx1) +
               w10 * rmn_at(cy1, cx0) + w11 * rmn_at(cy1, cx1);

  float s = rm1 + rm1n;
  if (s == 0.0f) s = 1e-6f;
  float a = rm1 / s;
  float b = rm1n / s;
  float bw00 = b * w00, bw01 = b * w01, bw10 = b * w10, bw11 = b * w11;

  // Fold the tap-column selection into per-pixel weights. The two x-taps of
  // each row live at columns {cx0, cx1} ⊆ {xb0, xb0+1} with
  // xb0 = min(cx0, W-2), so each row is ONE float2 load at xb0, and the
  // weights of lanes .x/.y are precomputed here (handles all clamp cases;
  // invalid taps already carry weight 0).
  int xb0 = min(cx0, W_ - 2);
  float wA0 = (cx0 == xb0 ? bw00 : 0.0f) + (cx1 == xb0 ? bw01 : 0.0f);
  float wB0 = (cx0 == xb0 + 1 ? bw00 : 0.0f) + (cx1 == xb0 + 1 ? bw01 : 0.0f);
  float wA1 = (cx0 == xb0 ? bw10 : 0.0f) + (cx1 == xb0 ? bw11 : 0.0f);
  float wB1 = (cx0 == xb0 + 1 ? bw10 : 0.0f) + (cx1 == xb0 + 1 ? bw11 : 0.0f);
  const int r0 = cy0 * W_ + xb0;  // row cy0 float2 base, always in-bounds
  const int r1 = cy1 * W_ + xb0;  // row cy1 float2 base

  const int c0 = cc * CCHUNK;
  const float* f1 = fmap1 + ((size_t)n * C_ + c0) * HW + p;
  const float* f2 = fmap1_next + ((size_t)n * C_ + c0) * HW;
  float* o = out + ((size_t)n * C_ + c0) * HW + p;

#pragma unroll 8
  for (int c = 0; c < CCHUNK; ++c) {
    const float* pc = f2 + (size_t)c * HW;
    float2 g0 = ld2(pc + r0);
    float2 g1 = ld2(pc + r1);
    float v1 = __builtin_nontemporal_load(&f1[(size_t)c * HW]);
    float wv = g0.x * wA0 + g0.y * wB0 + g1.x * wA1 + g1.y * wB1;
    __builtin_nontemporal_store(a * v1 + wv, &o[(size_t)c * HW]);
  }
}

// ---------------------------------------------------------------------------
// Kernel 2: convex upsample of coarse_flow channel 0 with up_mask, factor 4.
// (unchanged — isolates the fuse_kernel delta)
// ---------------------------------------------------------------------------
__global__ __launch_bounds__(W_) void upsample_kernel(
    const float* __restrict__ coarse_flow, const float* __restrict__ up_mask,
    float* __restrict__ out) {
  int b = blockIdx.x;
  int h = b % H_;
  b /= H_;
  int fy = b & 3;
  int n = b >> 2;
  int w = threadIdx.x;

  // 3x3 neighborhood of 4*flow[:,0], zero-padded
  const float* f = coarse_flow + (size_t)n * 2 * HW;
  float nb[9];
#pragma unroll
  for (int dy = 0; dy < 3; ++dy) {
#pragma unroll
    for (int dx = 0; dx < 3; ++dx) {
      int yy = h + dy - 1, xx = w + dx - 1;
      nb[dy * 3 + dx] = (yy >= 0 && yy < H_ && xx >= 0 && xx < W_)
                            ? 4.0f * f[yy * W_ + xx]
                            : 0.0f;
    }
  }

  const float* mb = up_mask + ((size_t)n * 144 * H_ + (size_t)h) * W_ + w;
  float4 res;
  float* resp = &res.x;
#pragma unroll
  for (int fx = 0; fx < 4; ++fx) {
    int cbase = fy * 4 + fx;
    float mv[9];
#pragma unroll
    for (int k = 0; k < 9; ++k)
      mv[k] = mb[(size_t)(k * 16 + cbase) * HW];
    float mx = mv[0];
#pragma unroll
    for (int k = 1; k < 9; ++k) mx = fmaxf(mx, mv[k]);
    float sum = 0.0f, acc = 0.0f;
#pragma unroll
    for (int k = 0; k < 9; ++k) {
      float e = __expf(mv[k] - mx);
      sum += e;
      acc += e * nb[k];
    }
    resp[fx] = acc / sum;
  }
  float* orow = out + (size_t)(n * SH + 4 * h + fy) * SW;
  *(float4*)(orow + 4 * w) = res;
}

extern "C" void kernel_launch(void* const* d_in, const int* in_sizes, int n_in,
                              void* d_out, int out_size, void* d_ws,
                              size_t ws_size, hipStream_t stream) {
  const float* fmap1 = (const float*)d_in[0];
  const float* fmap1_next = (const float*)d_in[1];
  const float* flow_left = (const float*)d_in[2];
  const float* mask1 = (const float*)d_in[3];
  const float* mask1_next = (const float*)d_in[4];
  const float* coarse_flow = (const float*)d_in[5];
  const float* up_mask = (const float*)d_in[6];
  float* out = (float*)d_out;

  fuse_kernel<<<FUSE_NWG, TPB, 0, stream>>>(fmap1, fmap1_next, flow_left,
                                            mask1, mask1_next, out);
  upsample_kernel<<<N_ * 4 * H_, W_, 0, stream>>>(coarse_flow, up_mask,
                                                  out + FUSED_SIZE);
}